// Round 13
// baseline (7537.115 us; speedup 1.0000x reference)
//
#include <hip/hip_runtime.h>
#include <hip/hip_bf16.h>

#define BB 64
#define VV 2048
#define ENCD 128
#define TT 100
#define EMBD 256
#define DECD 512
#define ATTD 256
#define NVOCAB 29

typedef unsigned int u32;
typedef unsigned short u16;
typedef __attribute__((ext_vector_type(2))) float f2;

__device__ __forceinline__ float sigf(float x) { return 1.0f / (1.0f + __expf(-x)); }
__device__ __forceinline__ u16 to_bf16(float f) {
    u32 u = __float_as_uint(f);
    u += 0x7fffu + ((u >> 16) & 1u);       // round-to-nearest-even
    return (u16)(u >> 16);
}

#if __has_builtin(__builtin_amdgcn_cvt_pk_fp8_f32) && __has_builtin(__builtin_amdgcn_cvt_pk_f32_fp8)
#define HAVE_FP8_CVT 1
#endif

// fp8 e4m3fn encode (RNE, subnormals flushed to 0: |err| <= 2^-6 on ~1.5% of values,
// negligible through the 256-term score sum)
__device__ __forceinline__ u32 fp8_enc(float f) {
#ifdef HAVE_FP8_CVT
    return (u32)__builtin_amdgcn_cvt_pk_fp8_f32(f, f, 0, false) & 0xffu;
#else
    u32 u = __float_as_uint(f);
    u32 s = (u >> 24) & 0x80u;
    u32 a = u & 0x7fffffffu;
    u32 r = a + 0x7FFFFu + ((a >> 20) & 1u);
    int v = (int)(r >> 20) - (120 << 3);
    if (v < 8) v = 0;
    if (v > 0x7E) v = 0x7E;
    return s | (u32)v;
#endif
}
__device__ __forceinline__ void fp8x4_dec(u32 u, float* o) {
#ifdef HAVE_FP8_CVT
    f2 lo = __builtin_amdgcn_cvt_pk_f32_fp8((int)u, false);
    f2 hi = __builtin_amdgcn_cvt_pk_f32_fp8((int)u, true);
    o[0] = lo[0]; o[1] = lo[1]; o[2] = hi[0]; o[3] = hi[1];
#else
    #pragma unroll
    for (int i = 0; i < 4; i++) {
        u32 byte = (u >> (8 * i)) & 0xffu;
        u32 s = (byte & 0x80u) << 24;
        u32 m = byte & 0x7fu;
        o[i] = m ? __uint_as_float(s | ((m + (120u << 3)) << 20)) : __uint_as_float(s);
    }
#endif
}

// ---------------- one-time init kernels ----------------

// W_decT[DEC][ATT], W_betaT[DEC][ENC], W2T[e][g] = W_ih[g][256+e], W_encT[k][a]
__global__ __launch_bounds__(256) void k_transpose(const float* __restrict__ W_dec,
                                                   const float* __restrict__ W_beta,
                                                   const float* __restrict__ W_ih,
                                                   const float* __restrict__ W_enc,
                                                   float* __restrict__ W_decT,
                                                   float* __restrict__ W_betaT,
                                                   float* __restrict__ W2T,
                                                   float* __restrict__ W_encT) {
    int i = blockIdx.x * 256 + threadIdx.x;
    if (i < DECD * ATTD) {
        int l = i / ATTD, a = i % ATTD;
        W_decT[i] = W_dec[a * DECD + l];
    } else if (i < DECD * ATTD + DECD * ENCD) {
        int j = i - DECD * ATTD;
        int l = j / ENCD, e = j % ENCD;
        W_betaT[j] = W_beta[e * DECD + l];
    } else if (i < DECD * ATTD + DECD * ENCD + ENCD * 2048) {
        int j = i - (DECD * ATTD + DECD * ENCD);
        int e = j >> 11, g = j & 2047;
        W2T[j] = W_ih[g * 384 + 256 + e];
    } else if (i < DECD * ATTD + DECD * ENCD + ENCD * 2048 + ENCD * ATTD) {
        int j = i - (DECD * ATTD + DECD * ENCD + ENCD * 2048);
        int k = j / ATTD, a = j % ATTD;
        W_encT[j] = W_enc[a * ENCD + k];
    }
}

// parallel mean partials: mpart[b][chunk][e] = sum_{v in 256-chunk} enc[b][v][e]
__global__ __launch_bounds__(256) void k_mean(const float* __restrict__ enc,
                                              float* __restrict__ mpart) {
    int b = blockIdx.x >> 3, chunk = blockIdx.x & 7;
    int t = threadIdx.x;
    int e = t & 127, h = t >> 7;           // h in {0,1}: front/back 128 voxels
    __shared__ float red[256];
    const float* src = enc + ((size_t)b * VV + chunk * 256 + h * 128) * ENCD + e;
    float s = 0.f;
    #pragma unroll 16
    for (int v = 0; v < 128; v++) s += src[(size_t)v * ENCD];
    red[t] = s;
    __syncthreads();
    if (t < 128) mpart[((size_t)b * 8 + chunk) * ENCD + t] = red[t] + red[t + 128];
}

// enc_att8[b][qq][a][vin] = fp8( enc[b][v][:] . W_enc[a][:] + b_enc[a] ),
// qq = v>>9 (quarter), vin = v&511. W_encT[k][a]: s_load_dwordx8 weight fetch.
__global__ __launch_bounds__(256) void k_enc_att(const float* __restrict__ enc,
                                                 const float* __restrict__ W_encT,
                                                 const float* __restrict__ b_enc,
                                                 unsigned char* __restrict__ enc_att8,
                                                 u16* __restrict__ enc_bf) {
    __shared__ float tile[64][ENCD + 1];
    int b = blockIdx.y, v0 = blockIdx.x * 64;
    int t = threadIdx.x;
    const float* src = enc + ((size_t)b * VV + v0) * ENCD;
    u16* dstb = enc_bf + ((size_t)b * VV + v0) * ENCD;
    for (int i = t; i < 64 * ENCD; i += 256) {
        float x = src[i];
        tile[i >> 7][i & 127] = x;
        dstb[i] = to_bf16(x);
    }
    __syncthreads();
    int vl = t & 63;
    int ag = __builtin_amdgcn_readfirstlane(t >> 6);   // wave-uniform -> scalar weight loads
    int qq = v0 >> 9, vin = (v0 & 511) + vl;
    unsigned char* dst8 = enc_att8 + (((size_t)(b * 4 + qq) * 256) << 9) + vin;
    for (int ao = 0; ao < 8; ao++) {
        int a0 = ag * 64 + ao * 8;
        float acc[8];
        #pragma unroll
        for (int j = 0; j < 8; j++) acc[j] = b_enc[a0 + j];
        const float* wT = W_encT + a0;                 // wave-uniform base
        #pragma unroll 8
        for (int k = 0; k < ENCD; k++) {               // unroll 8: cover ~120cy LDS latency
            float x = tile[vl][k];
            #pragma unroll
            for (int j = 0; j < 8; j++) acc[j] = fmaf(x, wT[k * ATTD + j], acc[j]);
        }
        #pragma unroll
        for (int j = 0; j < 8; j++)
            dst8[(size_t)(a0 + j) << 9] = (unsigned char)fp8_enc(acc[j]);
    }
}

// mean (from partials) -> h0,c0 -> dec_att0, gate0, xT(emb0 + h0 rows), lengths
__global__ __launch_bounds__(512) void k_init(const float* __restrict__ mpart,
                                              const int* __restrict__ lens,
                                              const int* __restrict__ captions,
                                              const float* __restrict__ emb_W,
                                              const float* __restrict__ W_init_h,
                                              const float* __restrict__ b_init_h,
                                              const float* __restrict__ W_init_c,
                                              const float* __restrict__ b_init_c,
                                              const float* __restrict__ W_decT,
                                              const float* __restrict__ b_dec,
                                              const float* __restrict__ W_betaT,
                                              const float* __restrict__ b_beta,
                                              float* __restrict__ c0,
                                              float* __restrict__ xT,
                                              float* __restrict__ dec_att,
                                              float* __restrict__ gate0,
                                              float* __restrict__ out_len) {
    __shared__ float mean[ENCD];
    __shared__ float h_s[DECD];
    int b = blockIdx.x, t = threadIdx.x;
    if (t < ENCD) {
        const float* mp = mpart + (size_t)b * 8 * ENCD + t;
        float s = mp[0];
        #pragma unroll
        for (int i = 1; i < 8; i++) s += mp[(size_t)i * ENCD];
        mean[t] = s * (1.0f / VV);
    }
    __syncthreads();
    {
        int d = t;
        float hh = b_init_h[d], cc = b_init_c[d];
        for (int k = 0; k < ENCD; k++) {
            hh = fmaf(mean[k], W_init_h[d * ENCD + k], hh);
            cc = fmaf(mean[k], W_init_c[d * ENCD + k], cc);
        }
        c0[b * DECD + d] = cc;
        h_s[d] = hh;
        xT[(384 + d) * BB + b] = hh;
    }
    __syncthreads();
    if (t < ATTD) {
        float s2 = b_dec[t];
        for (int l = 0; l < DECD; l++) s2 = fmaf(h_s[l], W_decT[l * ATTD + t], s2);
        dec_att[b * ATTD + t] = s2;
    } else if (t < ATTD + ENCD) {
        int ee = t - ATTD;
        float s2 = b_beta[ee];
        for (int l = 0; l < DECD; l++) s2 = fmaf(h_s[l], W_betaT[l * ENCD + ee], s2);
        gate0[b * ENCD + ee] = sigf(s2);
    } else {
        int k = t - 384;
        int cap = captions[b * TT + 0];
        xT[k * BB + b] = emb_W[cap * EMBD + k];
        xT[(k + 128) * BB + b] = emb_W[cap * EMBD + k + 128];
    }
    if (t == 0) out_len[b] = (float)lens[b];
}

// ---------------- per-step kernels (3 per step) ----------------

// blocks 0..255  : scores, one (b, 512-voxel quarter) per block (fp8 uint2 loads,
//                  4 a-slices/wave, LDS slice-combine) -> exp -> escoreT(bf16)
//                  + dpartT[4 slots] + pawe[4 slots]
// blocks 256..639: LSTM gate partial GEMM kc {0,1,3,4,5,6} (needs only prev-step xT)
__global__ __launch_bounds__(256) void k_att(const unsigned char* __restrict__ enc_att8,
                                             const u16* __restrict__ enc_bf,
                                             const float* __restrict__ dec_att,
                                             const float* __restrict__ w_full,
                                             const int* __restrict__ lens,
                                             const float* __restrict__ xT,
                                             const float* __restrict__ W_ih,
                                             const float* __restrict__ W_hh,
                                             const float* __restrict__ b_ih,
                                             const float* __restrict__ b_hh,
                                             u16* __restrict__ escoreT,
                                             float* __restrict__ dpartT,
                                             float* __restrict__ pawe,
                                             float* __restrict__ gates_part, int ts) {
    int blk = blockIdx.x, t = threadIdx.x;
    int lane = t & 63, wv = t >> 6;
    if (blk < 256) {
        int b = blk >> 2, qq = blk & 3;    // 512 voxels per block
        if (ts >= lens[b]) return;         // lengths sorted desc; uniform per block
        __shared__ float sp[4][512];       // per-a-slice partial scores
        __shared__ float esh[512];
        __shared__ float dred[4];
        __shared__ float redw[4][ENCD];
        {
            // wave wv covers a-slice [64*wv, 64*wv+64); lane covers voxels 8*lane..8*lane+7
            // u32 layout: idx = a*128 + (vin>>2) -> uint2 idx = a*64 + lane
            const uint2* sp2 = (const uint2*)((const u32*)enc_att8 +
                               (((size_t)(b * 4 + qq)) << 15)) + lane;
            const float* db = dec_att + b * ATTD + wv * 64;    // wave-uniform -> s_load
            const float* wf = w_full + wv * 64;
            float acc[8];
            #pragma unroll
            for (int j = 0; j < 8; j++) acc[j] = 0.f;
            #pragma unroll 16
            for (int i = 0; i < 64; i++) {
                uint2 u = sp2[(size_t)(wv * 64 + i) * 64];     // 512B row stride
                float x[8];
                fp8x4_dec(u.x, x);
                fp8x4_dec(u.y, x + 4);
                float da = db[i], wfv = wf[i];                 // b_full dropped (shift-inv)
                #pragma unroll
                for (int j = 0; j < 8; j++)
                    acc[j] = fmaf(fmaxf(x[j] + da, 0.f), wfv, acc[j]);
            }
            #pragma unroll
            for (int j = 0; j < 2; j++)
                *(float4*)&sp[wv][8 * lane + 4 * j] =
                    make_float4(acc[4 * j], acc[4 * j + 1], acc[4 * j + 2], acc[4 * j + 3]);
        }
        __syncthreads();
        // thread t finishes voxels 2t..2t+1 (slice partials combined in fixed order)
        float sv[2];
        #pragma unroll
        for (int j = 0; j < 2; j++)
            sv[j] = ((sp[0][2 * t + j] + sp[1][2 * t + j]) + sp[2][2 * t + j]) + sp[3][2 * t + j];
        float e0 = __expf(sv[0]), e1 = __expf(sv[1]);
        u32 pk = (u32)to_bf16(e0) | ((u32)to_bf16(e1) << 16);
        ((u32*)escoreT)[(((size_t)ts * BB + b) * VV + (qq << 9)) / 2 + t] = pk;
        esh[2 * t] = e0; esh[2 * t + 1] = e1;
        float ss = e0 + e1;
        for (int o = 32; o > 0; o >>= 1) ss += __shfl_down(ss, o);
        if (lane == 0) dred[wv] = ss;
        __syncthreads();
        if (t == 0) dpartT[((size_t)ts * BB + b) * 4 + qq] =
                        dred[0] + dred[1] + dred[2] + dred[3];
        // awe partial from bf16 encoder, e-pairs packed in u32
        const u32* eb = (const u32*)enc_bf + ((size_t)b * VV + (qq << 9)) * (ENCD / 2) + lane;
        float a0 = 0.f, a1 = 0.f;
        #pragma unroll 32
        for (int vv = wv; vv < 512; vv += 4) {
            u32 u = eb[(size_t)vv * 64];
            float sc = esh[vv];            // wave-uniform -> broadcast
            a0 = fmaf(__uint_as_float(u << 16), sc, a0);
            a1 = fmaf(__uint_as_float(u & 0xffff0000u), sc, a1);
        }
        redw[wv][2 * lane] = a0;
        redw[wv][2 * lane + 1] = a1;
        __syncthreads();
        if (t < ENCD)
            pawe[((size_t)b * 4 + qq) * ENCD + t] =
                redw[0][t] + redw[1][t] + redw[2][t] + redw[3][t];
    } else {
        int idx = blk - 256;
        int kcp = idx >> 6;                // slot 0..5
        int kc = kcp < 2 ? kcp : kcp + 1;  // K chunk {0,1,3,4,5,6}
        int gt = idx & 63;
        int gbase = gt * 32 + wv * 8;
        int gb = __builtin_amdgcn_readfirstlane(gbase);   // scalar weight addressing
        int k0 = kc * 128;
        float acc[8];
        #pragma unroll
        for (int j = 0; j < 8; j++)
            acc[j] = (kc == 0) ? (b_ih[gb + j] + b_hh[gb + j]) : 0.f;
        if (kc < 2) {                       // emb columns 0..255
            #pragma unroll 16
            for (int kk = 0; kk < 128; kk++) {
                float xv = xT[(k0 + kk) * BB + lane];
                #pragma unroll
                for (int j = 0; j < 8; j++)
                    acc[j] = fmaf(xv, W_ih[(gb + j) * 384 + k0 + kk], acc[j]);
            }
        } else {                            // h columns (W_hh cols 0..511)
            const float* Wh = W_hh + (k0 - 384);
            #pragma unroll 16
            for (int kk = 0; kk < 128; kk++) {
                float xv = xT[(k0 + kk) * BB + lane];
                #pragma unroll
                for (int j = 0; j < 8; j++)
                    acc[j] = fmaf(xv, Wh[(gb + j) * DECD + kk], acc[j]);
            }
        }
        float4* o4 = (float4*)(gates_part + ((size_t)kcp * BB + lane) * 2048 + gbase);
        o4[0] = make_float4(acc[0], acc[1], acc[2], acc[3]);
        o4[1] = make_float4(acc[4], acc[5], acc[6], acc[7]);
    }
}

// kc2 as a batched GEMM over b: 16 blocks x 512; block owns 128-gate slice.
// Builds gawe[64][128] in LDS (redundant across blocks, cheap), reads its
// W2T slice ONCE (64 KB vs k_cell's old 1 MB/block x 256 blocks), writes
// kc2 -> gates_part slot 6. e-summation order matches the old in-cell loop.
__global__ __launch_bounds__(512) void k_kc2(const float* __restrict__ pawe,
                                             const float* __restrict__ dpartT,
                                             const float* __restrict__ gate0,
                                             const float* __restrict__ gate1,
                                             const float* __restrict__ W2T,
                                             float* __restrict__ gates_part, int ts) {
    __shared__ float gawe_s[BB][ENCD];     // 32 KB
    __shared__ float kc2_s[BB][128];       // 32 KB
    int t = threadIdx.x;
    int go = blockIdx.x * 128;
    const float* gprev = (ts & 1) ? gate1 : gate0;
    #pragma unroll
    for (int i = 0; i < 16; i++) {
        int idx = t + i * 512;
        int b = idx >> 7, e = idx & 127;
        const float* dp = dpartT + ((size_t)ts * BB + b) * 4;
        float inv = 1.0f / ((dp[0] + dp[1]) + (dp[2] + dp[3]));
        const float* pw = pawe + (size_t)b * 4 * ENCD + e;
        float aw = ((pw[0] + pw[ENCD]) + (pw[2 * ENCD] + pw[3 * ENCD])) * inv;
        gawe_s[b][e] = gprev[b * ENCD + e] * aw;
    }
    __syncthreads();
    {
        int g = go + (t & 127);
        int b0 = (t >> 7) * 16;
        float acc[16];
        #pragma unroll
        for (int j = 0; j < 16; j++) acc[j] = 0.f;
        #pragma unroll 8
        for (int e = 0; e < ENCD; e++) {
            float w = W2T[(size_t)e * 2048 + g];
            #pragma unroll
            for (int j = 0; j < 16; j++)
                acc[j] = fmaf(w, gawe_s[b0 + j][e], acc[j]);   // LDS broadcast
        }
        #pragma unroll
        for (int j = 0; j < 16; j++) kc2_s[b0 + j][t & 127] = acc[j];
    }
    __syncthreads();
    #pragma unroll
    for (int i = 0; i < 16; i++) {         // coalesced write to slot 6
        int idx = t + i * 512;
        int b = idx >> 7, gg = idx & 127;
        gates_part[((size_t)6 * BB + b) * 2048 + go + gg] = kc2_s[b][gg];
    }
}

// 4 parts per b (256 blocks x 512 = full GPU): every part duplicates the cheap
// LDS-resident cell compute (slots 0..5 sum + slot6 kc2 + transcendentals -> h_s),
// downstream GEMVs split by output:
//  p0: cout + xT(h) + dec_att a[0,128);  p1: dec_att a[128,256);
//  p2: gate_next;                        p3: preds + emb(ts+1)
__global__ __launch_bounds__(512) void k_cell(const float* __restrict__ gates_part,
                                              const int* __restrict__ lens,
                                              const int* __restrict__ captions,
                                              const float* __restrict__ emb_W,
                                              const float* __restrict__ W_final,
                                              const float* __restrict__ b_final,
                                              const float* __restrict__ W_decT,
                                              const float* __restrict__ b_dec,
                                              const float* __restrict__ W_betaT,
                                              const float* __restrict__ b_beta,
                                              float* __restrict__ gate0,
                                              float* __restrict__ gate1,
                                              float* __restrict__ c0,
                                              float* __restrict__ c1,
                                              float* __restrict__ xT,
                                              float* __restrict__ dec_att,
                                              float* __restrict__ preds, int ts) {
    int b = blockIdx.x >> 2, part = blockIdx.x & 3;
    if (ts >= lens[b]) return;             // stale state = correct for masked rows
    __shared__ float h_s[DECD];
    __shared__ float red[512];
    int t = threadIdx.x;
    float* gnext = (ts & 1) ? gate0 : gate1;
    const float* cin  = (ts & 1) ? c1 : c0;
    float*       cout = (ts & 1) ? c0 : c1;
    {
        float gi = 0.f, gf = 0.f, gg = 0.f, go = 0.f;
        #pragma unroll
        for (int sc = 0; sc < 6; sc++) {
            const float* gp = gates_part + ((size_t)sc * BB + b) * 2048;
            gi += gp[t]; gf += gp[512 + t]; gg += gp[1024 + t]; go += gp[1536 + t];
        }
        const float* g6 = gates_part + ((size_t)6 * BB + b) * 2048;
        gi += g6[t]; gf += g6[512 + t]; gg += g6[1024 + t]; go += g6[1536 + t];
        gi = sigf(gi); gf = sigf(gf); go = sigf(go); gg = tanhf(gg);
        float cn = fmaf(gf, cin[b * DECD + t], gi * gg);
        float hn = go * tanhf(cn);
        h_s[t] = hn;
        if (part == 0) {
            cout[b * DECD + t] = cn;
            xT[(384 + t) * BB + b] = hn;
        }
    }
    __syncthreads();
    if (part < 2) {
        // dec_att: 128 a-outputs (a = (t&127)+part*128), K split 4 ways (qq = t>>7)
        int a = (t & 127) + part * 128, qq = t >> 7;
        float s = 0.f;
        const float* wd = W_decT + (size_t)qq * 128 * ATTD + a;
        #pragma unroll 16
        for (int l = 0; l < 128; l++) s = fmaf(h_s[qq * 128 + l], wd[(size_t)l * ATTD], s);
        red[t] = s;
        __syncthreads();
        if (t < 128)
            dec_att[b * ATTD + t + part * 128] =
                red[t] + red[t + 128] + red[t + 256] + red[t + 384] + b_dec[t + part * 128];
    } else if (part == 2) {
        int e = t & 127, qq = t >> 7;      // gate: 128 e, K split 4 ways
        float s = 0.f;
        const float* wb = W_betaT + (size_t)qq * 128 * ENCD + e;
        #pragma unroll 16
        for (int l = 0; l < 128; l++) s = fmaf(h_s[qq * 128 + l], wb[(size_t)l * ENCD], s);
        red[t] = s;
        __syncthreads();
        if (t < 128)
            gnext[b * ENCD + t] = sigf(red[t] + red[t + 128] + red[t + 256] + red[t + 384]
                                       + b_beta[t]);
    } else {
        int lane = t & 63, wv = t >> 6;    // predictions: 8 waves over 29 vocab
        for (int j = wv; j < NVOCAB; j += 8) {
            float s2 = 0.f;
            #pragma unroll
            for (int i = 0; i < 8; i++)
                s2 = fmaf(h_s[lane + 64 * i], W_final[j * DECD + lane + 64 * i], s2);
            for (int o = 32; o > 0; o >>= 1) s2 += __shfl_down(s2, o);
            if (lane == 0) preds[((size_t)b * TT + ts) * NVOCAB + j] = s2 + b_final[j];
        }
        if (t < 256 && ts + 1 < TT) {      // emb staging for ts+1
            int cap = captions[b * TT + ts + 1];
            xT[t * BB + b] = emb_W[cap * EMBD + t];
        }
    }
}

// bulk alphas: alphas[b][ts][v] = bf16(escoreT[ts][b][v]) / denom[ts][b]
__global__ __launch_bounds__(256) void k_alphas(const u16* __restrict__ escoreT,
                                                const float* __restrict__ dpartT,
                                                const int* __restrict__ lens,
                                                float* __restrict__ alphas) {
    int ts = blockIdx.x, b = blockIdx.y, t = threadIdx.x;
    if (ts >= lens[b]) return;             // output pre-zeroed
    const float* dp = dpartT + ((size_t)ts * BB + b) * 4;
    float inv = 1.0f / ((dp[0] + dp[1]) + (dp[2] + dp[3]));
    const u32* es = (const u32*)escoreT + ((size_t)ts * BB + b) * VV / 2;
    float2* al = (float2*)(alphas + ((size_t)b * TT + ts) * VV);
    #pragma unroll
    for (int i = t; i < VV / 2; i += 256) {
        u32 u = es[i];
        al[i] = make_float2(__uint_as_float(u << 16) * inv,
                            __uint_as_float(u & 0xffff0000u) * inv);
    }
}

extern "C" void kernel_launch(void* const* d_in, const int* in_sizes, int n_in,
                              void* d_out, int out_size, void* d_ws, size_t ws_size,
                              hipStream_t stream) {
    const float* enc      = (const float*)d_in[0];
    const int*   captions = (const int*)d_in[1];
    const int*   lens     = (const int*)d_in[2];
    const float* emb_W    = (const float*)d_in[3];
    const float* W_enc    = (const float*)d_in[4];
    const float* b_enc    = (const float*)d_in[5];
    const float* W_dec    = (const float*)d_in[6];
    const float* b_dec    = (const float*)d_in[7];
    const float* w_full   = (const float*)d_in[8];
    // d_in[9] b_full: unused — softmax is shift-invariant
    const float* W_ih     = (const float*)d_in[10];
    const float* b_ih     = (const float*)d_in[11];
    const float* W_hh     = (const float*)d_in[12];
    const float* b_hh     = (const float*)d_in[13];
    const float* W_init_h = (const float*)d_in[14];
    const float* b_init_h = (const float*)d_in[15];
    const float* W_init_c = (const float*)d_in[16];
    const float* b_init_c = (const float*)d_in[17];
    const float* W_beta   = (const float*)d_in[18];
    const float* b_beta   = (const float*)d_in[19];
    const float* W_final  = (const float*)d_in[20];
    const float* b_final  = (const float*)d_in[21];

    float* preds   = (float*)d_out;                      // [B][T][VOCAB]
    float* alphas  = preds + (size_t)BB * TT * NVOCAB;   // [B][T][V]
    float* out_len = alphas + (size_t)BB * TT * VV;      // [B] (as float)

    char* ws = (char*)d_ws;
    size_t off = 0;
    auto alloc = [&](size_t bytes) {
        char* p = ws + off;
        off += (bytes + 255) & ~(size_t)255;
        return p;
    };
    unsigned char* enc_att8 = (unsigned char*)alloc((size_t)BB * ATTD * VV);   // 33.5 MB fp8
    u16*   enc_bf     = (u16*)  alloc((size_t)BB * VV * ENCD * sizeof(u16));   // 33.5 MB
    u16*   escoreT    = (u16*)  alloc((size_t)TT * BB * VV * sizeof(u16));     // 26.2 MB
    float* dpartT     = (float*)alloc((size_t)TT * BB * 4 * sizeof(float));
    float* pawe       = (float*)alloc((size_t)BB * 4 * ENCD * sizeof(float));
    float* dec_att    = (float*)alloc((size_t)BB * ATTD * sizeof(float));
    float* gate0      = (float*)alloc((size_t)BB * ENCD * sizeof(float));
    float* gate1      = (float*)alloc((size_t)BB * ENCD * sizeof(float));
    float* xT         = (float*)alloc((size_t)896 * BB * sizeof(float));
    float* gates_part = (float*)alloc((size_t)7 * BB * 2048 * sizeof(float));  // 7 slots
    float* c0         = (float*)alloc((size_t)BB * DECD * sizeof(float));
    float* c1         = (float*)alloc((size_t)BB * DECD * sizeof(float));
    float* W_decT     = (float*)alloc((size_t)DECD * ATTD * sizeof(float));
    float* W_betaT    = (float*)alloc((size_t)DECD * ENCD * sizeof(float));
    float* W2T        = (float*)alloc((size_t)ENCD * 2048 * sizeof(float));
    float* W_encT     = (float*)alloc((size_t)ENCD * ATTD * sizeof(float));
    float* mpart      = (float*)alloc((size_t)BB * 8 * ENCD * sizeof(float));

    // masked (b,t) outputs must be exactly 0 (slot buffers need no zero-init:
    // always written by the same step that reads them)
    hipMemsetAsync(d_out, 0, (size_t)out_size * sizeof(float), stream);

    k_transpose<<<1920, 256, 0, stream>>>(W_dec, W_beta, W_ih, W_enc,
                                          W_decT, W_betaT, W2T, W_encT);
    k_mean<<<BB * 8, 256, 0, stream>>>(enc, mpart);
    k_enc_att<<<dim3(VV / 64, BB), 256, 0, stream>>>(enc, W_encT, b_enc, enc_att8, enc_bf);
    k_init<<<BB, 512, 0, stream>>>(mpart, lens, captions, emb_W, W_init_h, b_init_h,
                                   W_init_c, b_init_c, W_decT, b_dec, W_betaT, b_beta,
                                   c0, xT, dec_att, gate0, out_len);

    for (int t = 0; t < TT; t++) {
        k_att<<<640, 256, 0, stream>>>(enc_att8, enc_bf, dec_att, w_full, lens, xT,
                                       W_ih, W_hh, b_ih, b_hh, escoreT, dpartT, pawe,
                                       gates_part, t);
        k_kc2<<<16, 512, 0, stream>>>(pawe, dpartT, gate0, gate1, W2T, gates_part, t);
        k_cell<<<256, 512, 0, stream>>>(gates_part, lens, captions, emb_W,
                                        W_final, b_final, W_decT, b_dec, W_betaT,
                                        b_beta, gate0, gate1, c0, c1, xT, dec_att,
                                        preds, t);
    }
    k_alphas<<<dim3(TT, BB), 256, 0, stream>>>(escoreT, dpartT, lens, alphas);
}

// Round 14
// 4430.121 us; speedup vs baseline: 1.7013x; 1.7013x over previous
//
#include <hip/hip_runtime.h>
#include <hip/hip_bf16.h>

#define BB 64
#define VV 2048
#define ENCD 128
#define TT 100
#define EMBD 256
#define DECD 512
#define ATTD 256
#define NVOCAB 29

typedef unsigned int u32;
typedef unsigned short u16;
typedef __attribute__((ext_vector_type(2))) float f2;

__device__ __forceinline__ float sigf(float x) { return 1.0f / (1.0f + __expf(-x)); }
__device__ __forceinline__ u16 to_bf16(float f) {
    u32 u = __float_as_uint(f);
    u += 0x7fffu + ((u >> 16) & 1u);       // round-to-nearest-even
    return (u16)(u >> 16);
}

#if __has_builtin(__builtin_amdgcn_cvt_pk_fp8_f32) && __has_builtin(__builtin_amdgcn_cvt_pk_f32_fp8)
#define HAVE_FP8_CVT 1
#endif

// fp8 e4m3fn encode (RNE, subnormals flushed to 0: |err| <= 2^-6 on ~1.5% of values,
// negligible through the 256-term score sum)
__device__ __forceinline__ u32 fp8_enc(float f) {
#ifdef HAVE_FP8_CVT
    return (u32)__builtin_amdgcn_cvt_pk_fp8_f32(f, f, 0, false) & 0xffu;
#else
    u32 u = __float_as_uint(f);
    u32 s = (u >> 24) & 0x80u;
    u32 a = u & 0x7fffffffu;
    u32 r = a + 0x7FFFFu + ((a >> 20) & 1u);
    int v = (int)(r >> 20) - (120 << 3);
    if (v < 8) v = 0;
    if (v > 0x7E) v = 0x7E;
    return s | (u32)v;
#endif
}
__device__ __forceinline__ void fp8x4_dec(u32 u, float* o) {
#ifdef HAVE_FP8_CVT
    f2 lo = __builtin_amdgcn_cvt_pk_f32_fp8((int)u, false);
    f2 hi = __builtin_amdgcn_cvt_pk_f32_fp8((int)u, true);
    o[0] = lo[0]; o[1] = lo[1]; o[2] = hi[0]; o[3] = hi[1];
#else
    #pragma unroll
    for (int i = 0; i < 4; i++) {
        u32 byte = (u >> (8 * i)) & 0xffu;
        u32 s = (byte & 0x80u) << 24;
        u32 m = byte & 0x7fu;
        o[i] = m ? __uint_as_float(s | ((m + (120u << 3)) << 20)) : __uint_as_float(s);
    }
#endif
}

// ---------------- one-time init kernels ----------------

// W_decT[DEC][ATT], W_betaT[DEC][ENC], W2T[e][g] = W_ih[g][256+e], W_encT[k][a]
__global__ __launch_bounds__(256) void k_transpose(const float* __restrict__ W_dec,
                                                   const float* __restrict__ W_beta,
                                                   const float* __restrict__ W_ih,
                                                   const float* __restrict__ W_enc,
                                                   float* __restrict__ W_decT,
                                                   float* __restrict__ W_betaT,
                                                   float* __restrict__ W2T,
                                                   float* __restrict__ W_encT) {
    int i = blockIdx.x * 256 + threadIdx.x;
    if (i < DECD * ATTD) {
        int l = i / ATTD, a = i % ATTD;
        W_decT[i] = W_dec[a * DECD + l];
    } else if (i < DECD * ATTD + DECD * ENCD) {
        int j = i - DECD * ATTD;
        int l = j / ENCD, e = j % ENCD;
        W_betaT[j] = W_beta[e * DECD + l];
    } else if (i < DECD * ATTD + DECD * ENCD + ENCD * 2048) {
        int j = i - (DECD * ATTD + DECD * ENCD);
        int e = j >> 11, g = j & 2047;
        W2T[j] = W_ih[g * 384 + 256 + e];
    } else if (i < DECD * ATTD + DECD * ENCD + ENCD * 2048 + ENCD * ATTD) {
        int j = i - (DECD * ATTD + DECD * ENCD + ENCD * 2048);
        int k = j / ATTD, a = j % ATTD;
        W_encT[j] = W_enc[a * ENCD + k];
    }
}

// parallel mean partials: mpart[b][chunk][e] = sum_{v in 256-chunk} enc[b][v][e]
__global__ __launch_bounds__(256) void k_mean(const float* __restrict__ enc,
                                              float* __restrict__ mpart) {
    int b = blockIdx.x >> 3, chunk = blockIdx.x & 7;
    int t = threadIdx.x;
    int e = t & 127, h = t >> 7;           // h in {0,1}: front/back 128 voxels
    __shared__ float red[256];
    const float* src = enc + ((size_t)b * VV + chunk * 256 + h * 128) * ENCD + e;
    float s = 0.f;
    #pragma unroll 16
    for (int v = 0; v < 128; v++) s += src[(size_t)v * ENCD];
    red[t] = s;
    __syncthreads();
    if (t < 128) mpart[((size_t)b * 8 + chunk) * ENCD + t] = red[t] + red[t + 128];
}

// enc_att8[b][qq][a][vin] = fp8( enc[b][v][:] . W_enc[a][:] + b_enc[a] ),
// qq = v>>9 (quarter), vin = v&511. W_encT[k][a]: s_load_dwordx8 weight fetch.
__global__ __launch_bounds__(256) void k_enc_att(const float* __restrict__ enc,
                                                 const float* __restrict__ W_encT,
                                                 const float* __restrict__ b_enc,
                                                 unsigned char* __restrict__ enc_att8,
                                                 u16* __restrict__ enc_bf) {
    __shared__ float tile[64][ENCD + 1];
    int b = blockIdx.y, v0 = blockIdx.x * 64;
    int t = threadIdx.x;
    const float* src = enc + ((size_t)b * VV + v0) * ENCD;
    u16* dstb = enc_bf + ((size_t)b * VV + v0) * ENCD;
    for (int i = t; i < 64 * ENCD; i += 256) {
        float x = src[i];
        tile[i >> 7][i & 127] = x;
        dstb[i] = to_bf16(x);
    }
    __syncthreads();
    int vl = t & 63;
    int ag = __builtin_amdgcn_readfirstlane(t >> 6);   // wave-uniform -> scalar weight loads
    int qq = v0 >> 9, vin = (v0 & 511) + vl;
    unsigned char* dst8 = enc_att8 + (((size_t)(b * 4 + qq) * 256) << 9) + vin;
    for (int ao = 0; ao < 8; ao++) {
        int a0 = ag * 64 + ao * 8;
        float acc[8];
        #pragma unroll
        for (int j = 0; j < 8; j++) acc[j] = b_enc[a0 + j];
        const float* wT = W_encT + a0;                 // wave-uniform base
        #pragma unroll 8
        for (int k = 0; k < ENCD; k++) {               // unroll 8: cover ~120cy LDS latency
            float x = tile[vl][k];
            #pragma unroll
            for (int j = 0; j < 8; j++) acc[j] = fmaf(x, wT[k * ATTD + j], acc[j]);
        }
        #pragma unroll
        for (int j = 0; j < 8; j++)
            dst8[(size_t)(a0 + j) << 9] = (unsigned char)fp8_enc(acc[j]);
    }
}

// mean (from partials) -> h0,c0 -> dec_att0, gate0, xT(emb0 + h0 rows), lengths
__global__ __launch_bounds__(512) void k_init(const float* __restrict__ mpart,
                                              const int* __restrict__ lens,
                                              const int* __restrict__ captions,
                                              const float* __restrict__ emb_W,
                                              const float* __restrict__ W_init_h,
                                              const float* __restrict__ b_init_h,
                                              const float* __restrict__ W_init_c,
                                              const float* __restrict__ b_init_c,
                                              const float* __restrict__ W_decT,
                                              const float* __restrict__ b_dec,
                                              const float* __restrict__ W_betaT,
                                              const float* __restrict__ b_beta,
                                              float* __restrict__ c0,
                                              float* __restrict__ xT,
                                              float* __restrict__ dec_att,
                                              float* __restrict__ gate0,
                                              float* __restrict__ out_len) {
    __shared__ float mean[ENCD];
    __shared__ float h_s[DECD];
    int b = blockIdx.x, t = threadIdx.x;
    if (t < ENCD) {
        const float* mp = mpart + (size_t)b * 8 * ENCD + t;
        float s = mp[0];
        #pragma unroll
        for (int i = 1; i < 8; i++) s += mp[(size_t)i * ENCD];
        mean[t] = s * (1.0f / VV);
    }
    __syncthreads();
    {
        int d = t;
        float hh = b_init_h[d], cc = b_init_c[d];
        for (int k = 0; k < ENCD; k++) {
            hh = fmaf(mean[k], W_init_h[d * ENCD + k], hh);
            cc = fmaf(mean[k], W_init_c[d * ENCD + k], cc);
        }
        c0[b * DECD + d] = cc;
        h_s[d] = hh;
        xT[(384 + d) * BB + b] = hh;
    }
    __syncthreads();
    if (t < ATTD) {
        float s2 = b_dec[t];
        for (int l = 0; l < DECD; l++) s2 = fmaf(h_s[l], W_decT[l * ATTD + t], s2);
        dec_att[b * ATTD + t] = s2;
    } else if (t < ATTD + ENCD) {
        int ee = t - ATTD;
        float s2 = b_beta[ee];
        for (int l = 0; l < DECD; l++) s2 = fmaf(h_s[l], W_betaT[l * ENCD + ee], s2);
        gate0[b * ENCD + ee] = sigf(s2);
    } else {
        int k = t - 384;
        int cap = captions[b * TT + 0];
        xT[k * BB + b] = emb_W[cap * EMBD + k];
        xT[(k + 128) * BB + b] = emb_W[cap * EMBD + k + 128];
    }
    if (t == 0) out_len[b] = (float)lens[b];
}

// ---------------- per-step kernels (2 per step) ----------------

// blocks 0..255  : scores, one (b, 512-voxel quarter) per block (fp8 uint2 loads,
//                  4 a-slices/wave, LDS slice-combine) -> exp -> escoreT(bf16)
//                  + dpartT[4 slots] + pawe[4 slots]
// blocks 256..639: LSTM gate partial GEMM kc {0,1,3,4,5,6} (needs only prev-step xT)
__global__ __launch_bounds__(256) void k_att(const unsigned char* __restrict__ enc_att8,
                                             const u16* __restrict__ enc_bf,
                                             const float* __restrict__ dec_att,
                                             const float* __restrict__ w_full,
                                             const int* __restrict__ lens,
                                             const float* __restrict__ xT,
                                             const float* __restrict__ W_ih,
                                             const float* __restrict__ W_hh,
                                             const float* __restrict__ b_ih,
                                             const float* __restrict__ b_hh,
                                             u16* __restrict__ escoreT,
                                             float* __restrict__ dpartT,
                                             float* __restrict__ pawe,
                                             float* __restrict__ gates_part, int ts) {
    int blk = blockIdx.x, t = threadIdx.x;
    int lane = t & 63, wv = t >> 6;
    if (blk < 256) {
        int b = blk >> 2, qq = blk & 3;    // 512 voxels per block
        if (ts >= lens[b]) return;         // lengths sorted desc; uniform per block
        __shared__ float sp[4][512];       // per-a-slice partial scores
        __shared__ float esh[512];
        __shared__ float dred[4];
        __shared__ float redw[4][ENCD];
        {
            // wave wv covers a-slice [64*wv, 64*wv+64); lane covers voxels 8*lane..8*lane+7
            // u32 layout: idx = a*128 + (vin>>2) -> uint2 idx = a*64 + lane
            const uint2* sp2 = (const uint2*)((const u32*)enc_att8 +
                               (((size_t)(b * 4 + qq)) << 15)) + lane;
            const float* db = dec_att + b * ATTD + wv * 64;    // wave-uniform -> s_load
            const float* wf = w_full + wv * 64;
            float acc[8];
            #pragma unroll
            for (int j = 0; j < 8; j++) acc[j] = 0.f;
            #pragma unroll 16
            for (int i = 0; i < 64; i++) {
                uint2 u = sp2[(size_t)(wv * 64 + i) * 64];     // 512B row stride
                float x[8];
                fp8x4_dec(u.x, x);
                fp8x4_dec(u.y, x + 4);
                float da = db[i], wfv = wf[i];                 // b_full dropped (shift-inv)
                #pragma unroll
                for (int j = 0; j < 8; j++)
                    acc[j] = fmaf(fmaxf(x[j] + da, 0.f), wfv, acc[j]);
            }
            #pragma unroll
            for (int j = 0; j < 2; j++)
                *(float4*)&sp[wv][8 * lane + 4 * j] =
                    make_float4(acc[4 * j], acc[4 * j + 1], acc[4 * j + 2], acc[4 * j + 3]);
        }
        __syncthreads();
        // thread t finishes voxels 2t..2t+1 (slice partials combined in fixed order)
        float sv[2];
        #pragma unroll
        for (int j = 0; j < 2; j++)
            sv[j] = ((sp[0][2 * t + j] + sp[1][2 * t + j]) + sp[2][2 * t + j]) + sp[3][2 * t + j];
        float e0 = __expf(sv[0]), e1 = __expf(sv[1]);
        u32 pk = (u32)to_bf16(e0) | ((u32)to_bf16(e1) << 16);
        ((u32*)escoreT)[(((size_t)ts * BB + b) * VV + (qq << 9)) / 2 + t] = pk;
        esh[2 * t] = e0; esh[2 * t + 1] = e1;
        float ss = e0 + e1;
        for (int o = 32; o > 0; o >>= 1) ss += __shfl_down(ss, o);
        if (lane == 0) dred[wv] = ss;
        __syncthreads();
        if (t == 0) dpartT[((size_t)ts * BB + b) * 4 + qq] =
                        dred[0] + dred[1] + dred[2] + dred[3];
        // awe partial from bf16 encoder, e-pairs packed in u32
        const u32* eb = (const u32*)enc_bf + ((size_t)b * VV + (qq << 9)) * (ENCD / 2) + lane;
        float a0 = 0.f, a1 = 0.f;
        #pragma unroll 32
        for (int vv = wv; vv < 512; vv += 4) {
            u32 u = eb[(size_t)vv * 64];
            float sc = esh[vv];            // wave-uniform -> broadcast
            a0 = fmaf(__uint_as_float(u << 16), sc, a0);
            a1 = fmaf(__uint_as_float(u & 0xffff0000u), sc, a1);
        }
        redw[wv][2 * lane] = a0;
        redw[wv][2 * lane + 1] = a1;
        __syncthreads();
        if (t < ENCD)
            pawe[((size_t)b * 4 + qq) * ENCD + t] =
                redw[0][t] + redw[1][t] + redw[2][t] + redw[3][t];
    } else {
        int idx = blk - 256;
        int kcp = idx >> 6;                // slot 0..5
        int kc = kcp < 2 ? kcp : kcp + 1;  // K chunk {0,1,3,4,5,6}
        int gt = idx & 63;
        int gbase = gt * 32 + wv * 8;
        int gb = __builtin_amdgcn_readfirstlane(gbase);   // scalar weight addressing
        int k0 = kc * 128;
        float acc[8];
        #pragma unroll
        for (int j = 0; j < 8; j++)
            acc[j] = (kc == 0) ? (b_ih[gb + j] + b_hh[gb + j]) : 0.f;
        if (kc < 2) {                       // emb columns 0..255
            #pragma unroll 16
            for (int kk = 0; kk < 128; kk++) {
                float xv = xT[(k0 + kk) * BB + lane];
                #pragma unroll
                for (int j = 0; j < 8; j++)
                    acc[j] = fmaf(xv, W_ih[(gb + j) * 384 + k0 + kk], acc[j]);
            }
        } else {                            // h columns (W_hh cols 0..511)
            const float* Wh = W_hh + (k0 - 384);
            #pragma unroll 16
            for (int kk = 0; kk < 128; kk++) {
                float xv = xT[(k0 + kk) * BB + lane];
                #pragma unroll
                for (int j = 0; j < 8; j++)
                    acc[j] = fmaf(xv, Wh[(gb + j) * DECD + kk], acc[j]);
            }
        }
        float4* o4 = (float4*)(gates_part + ((size_t)kcp * BB + lane) * 2048 + gbase);
        o4[0] = make_float4(acc[0], acc[1], acc[2], acc[3]);
        o4[1] = make_float4(acc[4], acc[5], acc[6], acc[7]);
    }
}

// 4 parts per b (256 blocks x 512 = full GPU): every part duplicates the cheap
// LDS-resident cell compute (gawe + gates sum + kc2 + transcendentals -> h_s),
// downstream GEMVs split by output:
//  p0: cout + xT(h) + dec_att a[0,128);  p1: dec_att a[128,256);
//  p2: gate_next;                        p3: preds + emb(ts+1)
__global__ __launch_bounds__(512) void k_cell(const float* __restrict__ gates_part,
                                              const float* __restrict__ dpartT,
                                              const float* __restrict__ pawe,
                                              const int* __restrict__ lens,
                                              const int* __restrict__ captions,
                                              const float* __restrict__ emb_W,
                                              const float* __restrict__ W2T,
                                              const float* __restrict__ W_final,
                                              const float* __restrict__ b_final,
                                              const float* __restrict__ W_decT,
                                              const float* __restrict__ b_dec,
                                              const float* __restrict__ W_betaT,
                                              const float* __restrict__ b_beta,
                                              float* __restrict__ gate0,
                                              float* __restrict__ gate1,
                                              float* __restrict__ c0,
                                              float* __restrict__ c1,
                                              float* __restrict__ xT,
                                              float* __restrict__ dec_att,
                                              float* __restrict__ preds, int ts) {
    int b = blockIdx.x >> 2, part = blockIdx.x & 3;
    if (ts >= lens[b]) return;             // stale state = correct for masked rows
    __shared__ float gawe_s[ENCD];
    __shared__ float h_s[DECD];
    __shared__ float red[512];
    int t = threadIdx.x;
    const float* dp = dpartT + ((size_t)ts * BB + b) * 4;
    float inv = 1.0f / ((dp[0] + dp[1]) + (dp[2] + dp[3]));
    const float* gprev = (ts & 1) ? gate1 : gate0;   // ping-pong: read-prev/write-next
    float*       gnext = (ts & 1) ? gate0 : gate1;
    if (t < ENCD) {
        const float* pw = pawe + (size_t)b * 4 * ENCD + t;
        float aw = ((pw[0] + pw[ENCD]) + (pw[2 * ENCD] + pw[3 * ENCD])) * inv;
        gawe_s[t] = gprev[b * ENCD + t] * aw;
    }
    __syncthreads();
    const float* cin  = (ts & 1) ? c1 : c0;
    float*       cout = (ts & 1) ? c0 : c1;
    {
        float gi = 0.f, gf = 0.f, gg = 0.f, go = 0.f;
        #pragma unroll
        for (int sc = 0; sc < 6; sc++) {
            const float* gp = gates_part + ((size_t)sc * BB + b) * 2048;
            gi += gp[t]; gf += gp[512 + t]; gg += gp[1024 + t]; go += gp[1536 + t];
        }
        #pragma unroll 16
        for (int e = 0; e < ENCD; e++) {   // kc2: coalesced W2T rows, gawe broadcast
            const float* w = W2T + (size_t)e * 2048;
            float ge = gawe_s[e];
            gi = fmaf(w[t], ge, gi);
            gf = fmaf(w[512 + t], ge, gf);
            gg = fmaf(w[1024 + t], ge, gg);
            go = fmaf(w[1536 + t], ge, go);
        }
        gi = sigf(gi); gf = sigf(gf); go = sigf(go); gg = tanhf(gg);
        float cn = fmaf(gf, cin[b * DECD + t], gi * gg);
        float hn = go * tanhf(cn);
        h_s[t] = hn;
        if (part == 0) {
            cout[b * DECD + t] = cn;
            xT[(384 + t) * BB + b] = hn;
        }
    }
    __syncthreads();
    if (part < 2) {
        // dec_att: 128 a-outputs (a = (t&127)+part*128), K split 4 ways (qq = t>>7)
        int a = (t & 127) + part * 128, qq = t >> 7;
        float s = 0.f;
        const float* wd = W_decT + (size_t)qq * 128 * ATTD + a;
        #pragma unroll 16
        for (int l = 0; l < 128; l++) s = fmaf(h_s[qq * 128 + l], wd[(size_t)l * ATTD], s);
        red[t] = s;
        __syncthreads();
        if (t < 128)
            dec_att[b * ATTD + t + part * 128] =
                red[t] + red[t + 128] + red[t + 256] + red[t + 384] + b_dec[t + part * 128];
    } else if (part == 2) {
        int e = t & 127, qq = t >> 7;      // gate: 128 e, K split 4 ways
        float s = 0.f;
        const float* wb = W_betaT + (size_t)qq * 128 * ENCD + e;
        #pragma unroll 16
        for (int l = 0; l < 128; l++) s = fmaf(h_s[qq * 128 + l], wb[(size_t)l * ENCD], s);
        red[t] = s;
        __syncthreads();
        if (t < 128)
            gnext[b * ENCD + t] = sigf(red[t] + red[t + 128] + red[t + 256] + red[t + 384]
                                       + b_beta[t]);
    } else {
        int lane = t & 63, wv = t >> 6;    // predictions: 8 waves over 29 vocab
        for (int j = wv; j < NVOCAB; j += 8) {
            float s2 = 0.f;
            #pragma unroll
            for (int i = 0; i < 8; i++)
                s2 = fmaf(h_s[lane + 64 * i], W_final[j * DECD + lane + 64 * i], s2);
            for (int o = 32; o > 0; o >>= 1) s2 += __shfl_down(s2, o);
            if (lane == 0) preds[((size_t)b * TT + ts) * NVOCAB + j] = s2 + b_final[j];
        }
        if (t < 256 && ts + 1 < TT) {      // emb staging for ts+1
            int cap = captions[b * TT + ts + 1];
            xT[t * BB + b] = emb_W[cap * EMBD + t];
        }
    }
}

// bulk alphas: alphas[b][ts][v] = bf16(escoreT[ts][b][v]) / denom[ts][b]
__global__ __launch_bounds__(256) void k_alphas(const u16* __restrict__ escoreT,
                                                const float* __restrict__ dpartT,
                                                const int* __restrict__ lens,
                                                float* __restrict__ alphas) {
    int ts = blockIdx.x, b = blockIdx.y, t = threadIdx.x;
    if (ts >= lens[b]) return;             // output pre-zeroed
    const float* dp = dpartT + ((size_t)ts * BB + b) * 4;
    float inv = 1.0f / ((dp[0] + dp[1]) + (dp[2] + dp[3]));
    const u32* es = (const u32*)escoreT + ((size_t)ts * BB + b) * VV / 2;
    float2* al = (float2*)(alphas + ((size_t)b * TT + ts) * VV);
    #pragma unroll
    for (int i = t; i < VV / 2; i += 256) {
        u32 u = es[i];
        al[i] = make_float2(__uint_as_float(u << 16) * inv,
                            __uint_as_float(u & 0xffff0000u) * inv);
    }
}

extern "C" void kernel_launch(void* const* d_in, const int* in_sizes, int n_in,
                              void* d_out, int out_size, void* d_ws, size_t ws_size,
                              hipStream_t stream) {
    const float* enc      = (const float*)d_in[0];
    const int*   captions = (const int*)d_in[1];
    const int*   lens     = (const int*)d_in[2];
    const float* emb_W    = (const float*)d_in[3];
    const float* W_enc    = (const float*)d_in[4];
    const float* b_enc    = (const float*)d_in[5];
    const float* W_dec    = (const float*)d_in[6];
    const float* b_dec    = (const float*)d_in[7];
    const float* w_full   = (const float*)d_in[8];
    // d_in[9] b_full: unused — softmax is shift-invariant
    const float* W_ih     = (const float*)d_in[10];
    const float* b_ih     = (const float*)d_in[11];
    const float* W_hh     = (const float*)d_in[12];
    const float* b_hh     = (const float*)d_in[13];
    const float* W_init_h = (const float*)d_in[14];
    const float* b_init_h = (const float*)d_in[15];
    const float* W_init_c = (const float*)d_in[16];
    const float* b_init_c = (const float*)d_in[17];
    const float* W_beta   = (const float*)d_in[18];
    const float* b_beta   = (const float*)d_in[19];
    const float* W_final  = (const float*)d_in[20];
    const float* b_final  = (const float*)d_in[21];

    float* preds   = (float*)d_out;                      // [B][T][VOCAB]
    float* alphas  = preds + (size_t)BB * TT * NVOCAB;   // [B][T][V]
    float* out_len = alphas + (size_t)BB * TT * VV;      // [B] (as float)

    char* ws = (char*)d_ws;
    size_t off = 0;
    auto alloc = [&](size_t bytes) {
        char* p = ws + off;
        off += (bytes + 255) & ~(size_t)255;
        return p;
    };
    unsigned char* enc_att8 = (unsigned char*)alloc((size_t)BB * ATTD * VV);   // 33.5 MB fp8
    u16*   enc_bf     = (u16*)  alloc((size_t)BB * VV * ENCD * sizeof(u16));   // 33.5 MB
    u16*   escoreT    = (u16*)  alloc((size_t)TT * BB * VV * sizeof(u16));     // 26.2 MB
    float* dpartT     = (float*)alloc((size_t)TT * BB * 4 * sizeof(float));
    float* pawe       = (float*)alloc((size_t)BB * 4 * ENCD * sizeof(float));
    float* dec_att    = (float*)alloc((size_t)BB * ATTD * sizeof(float));
    float* gate0      = (float*)alloc((size_t)BB * ENCD * sizeof(float));
    float* gate1      = (float*)alloc((size_t)BB * ENCD * sizeof(float));
    float* xT         = (float*)alloc((size_t)896 * BB * sizeof(float));
    float* gates_part = (float*)alloc((size_t)6 * BB * 2048 * sizeof(float));
    float* c0         = (float*)alloc((size_t)BB * DECD * sizeof(float));
    float* c1         = (float*)alloc((size_t)BB * DECD * sizeof(float));
    float* W_decT     = (float*)alloc((size_t)DECD * ATTD * sizeof(float));
    float* W_betaT    = (float*)alloc((size_t)DECD * ENCD * sizeof(float));
    float* W2T        = (float*)alloc((size_t)ENCD * 2048 * sizeof(float));
    float* W_encT     = (float*)alloc((size_t)ENCD * ATTD * sizeof(float));
    float* mpart      = (float*)alloc((size_t)BB * 8 * ENCD * sizeof(float));

    // masked (b,t) outputs must be exactly 0 (slot buffers need no zero-init:
    // always written by the same step that reads them)
    hipMemsetAsync(d_out, 0, (size_t)out_size * sizeof(float), stream);

    k_transpose<<<1920, 256, 0, stream>>>(W_dec, W_beta, W_ih, W_enc,
                                          W_decT, W_betaT, W2T, W_encT);
    k_mean<<<BB * 8, 256, 0, stream>>>(enc, mpart);
    k_enc_att<<<dim3(VV / 64, BB), 256, 0, stream>>>(enc, W_encT, b_enc, enc_att8, enc_bf);
    k_init<<<BB, 512, 0, stream>>>(mpart, lens, captions, emb_W, W_init_h, b_init_h,
                                   W_init_c, b_init_c, W_decT, b_dec, W_betaT, b_beta,
                                   c0, xT, dec_att, gate0, out_len);

    for (int t = 0; t < TT; t++) {
        k_att<<<640, 256, 0, stream>>>(enc_att8, enc_bf, dec_att, w_full, lens, xT,
                                       W_ih, W_hh, b_ih, b_hh, escoreT, dpartT, pawe,
                                       gates_part, t);
        k_cell<<<256, 512, 0, stream>>>(gates_part, dpartT, pawe, lens, captions, emb_W,
                                        W2T, W_final, b_final, W_decT, b_dec, W_betaT,
                                        b_beta, gate0, gate1, c0, c1, xT, dec_att,
                                        preds, t);
    }
    k_alphas<<<dim3(TT, BB), 256, 0, stream>>>(escoreT, dpartT, lens, alphas);
}